// Round 12
// baseline (108.302 us; speedup 1.0000x reference)
//
#include <hip/hip_runtime.h>
#include <stdint.h>

// FullAttention B=2, N=M=2048, H=8, D=64, fp32 in/out, masks all-true.
// R12 = R11 skeleton with KT=128: half the barriers, 2x the per-barrier
// compute window so the global_load_lds vmcnt drain at __syncthreads is
// covered (theory: per-iter staging latency ~900cy > KT=64 compute window).
// LDS 128 KB -> 1 block/CU, 8 waves. 2 key-groups, S^T trick, permuted V
// (128-key tiles), in-LDS combine. 2 dispatches.

#define B_  2
#define N_  2048
#define M_  2048
#define H_  8
#define D_  64
#define KTL 128                                // keys per tile
#define MH  1024                               // keys per wave-group
#define NT_ (MH / KTL)                         // 8 tiles per group
#define QSCALE (0.125f * 1.44269504088896f)    // 1/sqrt(64) * log2(e)

typedef _Float16 f16;
typedef __attribute__((ext_vector_type(2))) __fp16 hf16x2;
typedef __attribute__((ext_vector_type(4))) _Float16 f16x4;
typedef __attribute__((ext_vector_type(8))) _Float16 f16x8;
typedef __attribute__((ext_vector_type(4))) float f32x4;

static __device__ __forceinline__ void load_lds16(const void* g, void* l) {
    __builtin_amdgcn_global_load_lds(
        (const __attribute__((address_space(1))) uint32_t*)g,
        (__attribute__((address_space(3))) uint32_t*)l, 16, 0, 0);
}

// ---- prep: job 0: K [B][M][H][D] fp32 -> [bh][m][d] f16
//            job 1: V [B][M][H][D] fp32 -> [bh][d][m_perm] f16; transpose +
//                   128-key permutation: key r=g&127 -> slot 32q+8hf+4s+j
//                   (hf=(r>>5)&3, s=(r>>4)&1, q=(r>>2)&3, j=r&3) so one b128
//                   staging granule = one PV A-frag pair.
__global__ __launch_bounds__(256)
void prep(const float* __restrict__ k, const float* __restrict__ v,
          f16* __restrict__ kh, f16* __restrict__ vh)
{
    const int tid = threadIdx.x;
    if (blockIdx.y == 0) {
        int i = blockIdx.x * 256 + tid;          // 524288 float4s
        int d4 = i & 15;
        int h  = (i >> 4) & 7;
        int n  = (i >> 7) & 2047;
        int b  = i >> 18;
        const float4 val = *reinterpret_cast<const float4*>(
            &k[(((size_t)b * M_ + n) * H_ + h) * D_ + d4 * 4]);
        f16x4 o = { (f16)val.x, (f16)val.y, (f16)val.z, (f16)val.w };
        *reinterpret_cast<f16x4*>(
            &kh[(((size_t)((b << 3) | h)) * M_ + n) * D_ + d4 * 4]) = o;
    } else {
        if (blockIdx.x >= 512) return;
        __shared__ float t[64][65];
        const int m0 = (blockIdx.x & 31) * 64;
        const int bh = blockIdx.x >> 5;
        const int b = bh >> 3, h = bh & 7;
        #pragma unroll
        for (int i = 0; i < 4; ++i) {
            int mloc = (tid >> 4) + i * 16;
            int d4   = (tid & 15) * 4;
            const float4 val = *reinterpret_cast<const float4*>(
                &v[(((size_t)b * M_ + m0 + mloc) * H_ + h) * D_ + d4]);
            t[mloc][d4 + 0] = val.x; t[mloc][d4 + 1] = val.y;
            t[mloc][d4 + 2] = val.z; t[mloc][d4 + 3] = val.w;
        }
        __syncthreads();
        #pragma unroll
        for (int p = 0; p < 4; ++p) {
            int idx = p * 256 + tid;
            int d = idx >> 4;
            int u = idx & 15;                    // local key group u*4..u*4+3
            const int g0 = m0 + u * 4;           // global key of group base
            const int r  = g0 & 127;
            const int hf = (r >> 5) & 3;
            const int s  = (r >> 4) & 1;
            const int qq = (r >> 2) & 3;
            const int slot = qq * 32 + hf * 8 + s * 4;   // permuted position
            f16x4 o = { (f16)t[u * 4 + 0][d], (f16)t[u * 4 + 1][d],
                        (f16)t[u * 4 + 2][d], (f16)t[u * 4 + 3][d] };
            *reinterpret_cast<f16x4*>(
                &vh[((size_t)bh * D_ + d) * M_ + (g0 & ~127) + slot]) = o;
        }
    }
}

// ---- main flash kernel: 8 waves, two key-halves, KT=128, in-LDS combine ----
__global__ __launch_bounds__(512, 2)
void fa_main(const float* __restrict__ q, const f16* __restrict__ kb,
             const f16* __restrict__ vt, float* __restrict__ out)
{
    // per grp: buf[2] x (K 16KB @0 + V 16KB @16384) = 65536 B; 2 grps = 128 KB.
    // combine overlay (post-loop): sC 16 KB @0, sL 256 B @131072.
    __shared__ __align__(16) char smem[131072 + 256];
    float* sC = (float*)smem;
    float* sL = (float*)(smem + 131072);

    const int tid  = threadIdx.x;
    const int wave = tid >> 6;
    const int w4   = wave & 3;          // wave within group (16 q-rows)
    const int grp  = wave >> 2;         // key half
    const int lane = tid & 63;
    const int quad = lane >> 4;
    const int l16  = lane & 15;

    f16* kB[2]; f16* vB[2];
    #pragma unroll
    for (int i = 0; i < 2; ++i) {
        kB[i] = (f16*)(smem + grp * 65536 + i * 32768);          // 128r x 128B
        vB[i] = (f16*)(smem + grp * 65536 + i * 32768 + 16384);  // 64r x 256B
    }

    const int qt = blockIdx.x;          // 0..31 (64 q-rows per block)
    const int bh = blockIdx.y;
    const int b  = bh >> 3;
    const int h  = bh & 7;

    const f16* kbase = kb + (size_t)bh * (M_ * D_) + (size_t)grp * MH * D_;
    const f16* vbase = vt + (size_t)bh * (D_ * M_) + (size_t)grp * MH;

    // Q fragments (B-operand: B[n=qrow=l16][k=quad*8+j])
    f16x8 qf[2];
    {
        const float* qrow = q + (((size_t)b * N_ + qt * 64 + w4 * 16 + l16) * H_ + h) * D_;
        #pragma unroll
        for (int kk = 0; kk < 2; ++kk) {
            const float4 a0 = *reinterpret_cast<const float4*>(&qrow[kk * 32 + quad * 8]);
            const float4 a1 = *reinterpret_cast<const float4*>(&qrow[kk * 32 + quad * 8 + 4]);
            qf[kk][0] = (f16)(a0.x * QSCALE); qf[kk][1] = (f16)(a0.y * QSCALE);
            qf[kk][2] = (f16)(a0.z * QSCALE); qf[kk][3] = (f16)(a0.w * QSCALE);
            qf[kk][4] = (f16)(a1.x * QSCALE); qf[kk][5] = (f16)(a1.y * QSCALE);
            qf[kk][6] = (f16)(a1.z * QSCALE); qf[kk][7] = (f16)(a1.w * QSCALE);
        }
    }

    f32x4 o2[4];                        // O^T accum: d = nt*16+quad*4+e, qrow = l16
    #pragma unroll
    for (int nt = 0; nt < 4; ++nt) o2[nt] = (f32x4){0.f, 0.f, 0.f, 0.f};
    float lp = 0.f;

    const int rloc = lane >> 3;                 // K staging: 8 rows/instr
    const int cswk = (lane & 7) ^ rloc;         // K source granule (8/row)
    const int rv   = lane >> 4;                 // V staging: 4 rows/instr
    const int cswv = (lane & 15) ^ ((w4 * 4 + rv) & 7);   // V source granule (16/row)

    // prologue: stage tile 0 -> buffer 0
    #pragma unroll
    for (int i = 0; i < 4; ++i) {
        const int r = i * 32 + w4 * 8 + rloc;
        load_lds16(kbase + (size_t)r * 64 + cswk * 8, &kB[0][(i * 32 + w4 * 8) * 64]);
        const int d = i * 16 + w4 * 4 + rv;
        load_lds16(vbase + (size_t)d * M_ + cswv * 8, &vB[0][(i * 16 + w4 * 4) * 128]);
    }

    #pragma unroll 2
    for (int t = 0; t < NT_; ++t) {
        const int cur = t & 1;
        __syncthreads();                // staging of tile t complete

        if (t + 1 < NT_) {
            const f16* kp = kbase + (size_t)(t + 1) * KTL * 64;
            const f16* vp = vbase + (size_t)(t + 1) * KTL;
            f16* kd = kB[cur ^ 1];
            f16* vd = vB[cur ^ 1];
            #pragma unroll
            for (int i = 0; i < 4; ++i) {
                const int r = i * 32 + w4 * 8 + rloc;
                load_lds16(kp + (size_t)r * 64 + cswk * 8, &kd[(i * 32 + w4 * 8) * 64]);
                const int d = i * 16 + w4 * 4 + rv;
                load_lds16(vp + (size_t)d * M_ + cswv * 8, &vd[(i * 16 + w4 * 4) * 128]);
            }
        }

        // ---- S^T = K·Q^T : 128 keys x 16 qrows; row = key = ct*16+quad*4+e
        const f16* ks = kB[cur];
        f32x4 st[8];
        #pragma unroll
        for (int ct = 0; ct < 8; ++ct) st[ct] = (f32x4){0.f, 0.f, 0.f, 0.f};
        #pragma unroll
        for (int ct = 0; ct < 8; ++ct) {
            #pragma unroll
            for (int kk = 0; kk < 2; ++kk) {
                const f16x8 kf = *reinterpret_cast<const f16x8*>(
                    &ks[(ct * 16 + l16) * 64 + (((kk * 4 + quad) ^ (l16 & 7)) * 8)]);
                st[ct] = __builtin_amdgcn_mfma_f32_16x16x32_f16(kf, qf[kk], st[ct], 0, 0, 0);
            }
        }

        // ---- P = 2^(S^T) via raw v_exp_f32; pack f16 B-frags; l partials
        f16x4 pf[8];
        #pragma unroll
        for (int ct = 0; ct < 8; ++ct) {
            const float p0 = __builtin_amdgcn_exp2f(st[ct][0]);
            const float p1 = __builtin_amdgcn_exp2f(st[ct][1]);
            const float p2 = __builtin_amdgcn_exp2f(st[ct][2]);
            const float p3 = __builtin_amdgcn_exp2f(st[ct][3]);
            lp += (p0 + p1) + (p2 + p3);
            union { hf16x2 h2[2]; f16x4 v4; } u;
            u.h2[0] = __builtin_amdgcn_cvt_pkrtz(p0, p1);
            u.h2[1] = __builtin_amdgcn_cvt_pkrtz(p2, p3);
            pf[ct] = u.v4;
        }

        // ---- O^T += V^T·P^T : b128 granule (quad*4+hf) = A-frags for ct=2hf,2hf+1
        const f16* vs = vB[cur];
        #pragma unroll
        for (int hf = 0; hf < 4; ++hf) {
            #pragma unroll
            for (int nt = 0; nt < 4; ++nt) {
                union { f16x8 v8; f16x4 v4[2]; } uu;
                uu.v8 = *reinterpret_cast<const f16x8*>(
                    &vs[(nt * 16 + l16) * 128 + (((quad * 4 + hf) ^ (l16 & 7)) * 8)]);
                o2[nt] = __builtin_amdgcn_mfma_f32_16x16x16f16(uu.v4[0], pf[2 * hf],     o2[nt], 0, 0, 0);
                o2[nt] = __builtin_amdgcn_mfma_f32_16x16x16f16(uu.v4[1], pf[2 * hf + 1], o2[nt], 0, 0, 0);
            }
        }
    }

    // ---- reduce l over quads
    float l = lp;
    l += __shfl_xor(l, 16, 64);
    l += __shfl_xor(l, 32, 64);

    __syncthreads();                    // all staging reads done; safe to overlay
    if (grp == 1) {
        const int base = (w4 * 64 + lane) * 16;
        #pragma unroll
        for (int nt = 0; nt < 4; ++nt)
            *reinterpret_cast<f32x4*>(&sC[base + nt * 4]) = o2[nt];
        if (quad == 0) sL[w4 * 16 + l16] = l;
    }
    __syncthreads();
    if (grp == 0) {
        const int base = (w4 * 64 + lane) * 16;
        const float inv = 1.0f / (l + sL[w4 * 16 + l16]);
        const size_t orow = (((size_t)b * N_ + qt * 64 + w4 * 16 + l16) * H_ + h) * D_;
        #pragma unroll
        for (int nt = 0; nt < 4; ++nt) {
            const f32x4 c = *reinterpret_cast<const f32x4*>(&sC[base + nt * 4]);
            float4 w;
            w.x = (o2[nt][0] + c[0]) * inv;
            w.y = (o2[nt][1] + c[1]) * inv;
            w.z = (o2[nt][2] + c[2]) * inv;
            w.w = (o2[nt][3] + c[3]) * inv;
            *reinterpret_cast<float4*>(&out[orow + nt * 16 + quad * 4]) = w;
        }
    }
}

extern "C" void kernel_launch(void* const* d_in, const int* in_sizes, int n_in,
                              void* d_out, int out_size, void* d_ws, size_t ws_size,
                              hipStream_t stream) {
    const float* q = (const float*)d_in[0];
    const float* k = (const float*)d_in[1];
    const float* v = (const float*)d_in[2];
    float* out = (float*)d_out;

    const size_t ESZ = (size_t)B_ * H_ * N_ * D_;   // 2097152
    f16* kh = (f16*)d_ws;                            // 4 MB
    f16* vh = kh + ESZ;                              // 4 MB

    prep<<<dim3(2048, 2), dim3(256), 0, stream>>>(k, v, kh, vh);
    fa_main<<<dim3(N_ / 64, B_ * H_), dim3(512), 0, stream>>>(q, kh, vh, out);
}

// Round 13
// 103.092 us; speedup vs baseline: 1.0505x; 1.0505x over previous
//
#include <hip/hip_runtime.h>
#include <stdint.h>

// FullAttention B=2, N=M=2048, H=8, D=64, fp32 in/out, masks all-true.
// R13 = R11 (best, 104.8) + VALU-issue surgery:
//  - all LDS read addresses precomputed as lane constants; ct/nt via ds_read
//    16-bit offset immediates; unroll-2 makes buffer bases static.
//    (identity: (4+quad)^x == (quad^x)^4 for quad<4 -> only 2 K bases, 2 V bases)
//  - PV fragments as two adjacent f16x4 loads (ds_read2_b64, no union repack).
//  - prep as 1D grid (2048 K-blocks + 512 V-blocks, no no-op dispatches).
// Structure unchanged: 512 thr, 2 key-groups, KT=64 double-buffered via
// global_load_lds, S^T trick, permuted V, raw v_exp_f32, in-LDS combine.

#define B_  2
#define N_  2048
#define M_  2048
#define H_  8
#define D_  64
#define KT  64
#define MH  1024                               // keys per wave-group
#define NT_ 16                                 // tiles per group
#define QSCALE (0.125f * 1.44269504088896f)    // 1/sqrt(64) * log2(e)

typedef _Float16 f16;
typedef __attribute__((ext_vector_type(2))) __fp16 hf16x2;
typedef __attribute__((ext_vector_type(4))) _Float16 f16x4;
typedef __attribute__((ext_vector_type(8))) _Float16 f16x8;
typedef __attribute__((ext_vector_type(4))) float f32x4;

static __device__ __forceinline__ void load_lds16(const void* g, void* l) {
    __builtin_amdgcn_global_load_lds(
        (const __attribute__((address_space(1))) uint32_t*)g,
        (__attribute__((address_space(3))) uint32_t*)l, 16, 0, 0);
}

// ---- prep (1D grid): blocks [0,2048): K cast; [2048,2560): V transpose+perm
__global__ __launch_bounds__(256)
void prep(const float* __restrict__ k, const float* __restrict__ v,
          f16* __restrict__ kh, f16* __restrict__ vh)
{
    const int tid = threadIdx.x;
    const int blk = blockIdx.x;
    if (blk < 2048) {
        int i = blk * 256 + tid;                 // 524288 float4s
        int d4 = i & 15;
        int h  = (i >> 4) & 7;
        int n  = (i >> 7) & 2047;
        int b  = i >> 18;
        const float4 val = *reinterpret_cast<const float4*>(
            &k[(((size_t)b * M_ + n) * H_ + h) * D_ + d4 * 4]);
        f16x4 o = { (f16)val.x, (f16)val.y, (f16)val.z, (f16)val.w };
        *reinterpret_cast<f16x4*>(
            &kh[(((size_t)((b << 3) | h)) * M_ + n) * D_ + d4 * 4]) = o;
    } else {
        __shared__ float t[64][65];
        const int vb = blk - 2048;               // 0..511
        const int m0 = (vb & 31) * 64;
        const int bh = vb >> 5;
        const int b = bh >> 3, h = bh & 7;
        #pragma unroll
        for (int i = 0; i < 4; ++i) {
            int mloc = (tid >> 4) + i * 16;
            int d4   = (tid & 15) * 4;
            const float4 val = *reinterpret_cast<const float4*>(
                &v[(((size_t)b * M_ + m0 + mloc) * H_ + h) * D_ + d4]);
            t[mloc][d4 + 0] = val.x; t[mloc][d4 + 1] = val.y;
            t[mloc][d4 + 2] = val.z; t[mloc][d4 + 3] = val.w;
        }
        __syncthreads();
        #pragma unroll
        for (int p = 0; p < 4; ++p) {
            int idx = p * 256 + tid;
            int d = idx >> 4;
            int u = idx & 15;                    // positions u*4 .. u*4+3
            const int kb = (u & 3) * 16 + (u >> 2) * 4;   // orig key base
            f16x4 o = { (f16)t[kb + 0][d], (f16)t[kb + 1][d],
                        (f16)t[kb + 2][d], (f16)t[kb + 3][d] };
            *reinterpret_cast<f16x4*>(
                &vh[((size_t)bh * D_ + d) * M_ + m0 + u * 4]) = o;
        }
    }
}

// ---- main flash kernel: 8 waves, two key-halves, in-LDS combine ----
__global__ __launch_bounds__(512, 4)
void fa_main(const float* __restrict__ q, const f16* __restrict__ kb,
             const f16* __restrict__ vt, float* __restrict__ out)
{
    // per grp: buf[2] x (K 8KB + V 8KB) = 32768 B; 2 grps = 65536 B.
    // combine overlay (post-loop): sC 16 KB @0, sL 256 B @65536.
    __shared__ __align__(16) char smem[65536 + 256];
    float* sC = (float*)smem;
    float* sL = (float*)(smem + 65536);

    const int tid  = threadIdx.x;
    const int wave = tid >> 6;
    const int w4   = wave & 3;          // wave within group (16 q-rows)
    const int grp  = wave >> 2;         // key half
    const int lane = tid & 63;
    const int quad = lane >> 4;
    const int l16  = lane & 15;

    const int qt = blockIdx.x;          // 0..31 (64 q-rows per block)
    const int bh = blockIdx.y;
    const int b  = bh >> 3;
    const int h  = bh & 7;

    const f16* kbase = kb + (size_t)bh * (M_ * D_) + (size_t)grp * MH * D_;
    const f16* vbase = vt + (size_t)bh * (D_ * M_) + (size_t)grp * MH;

    // Q fragments (B-operand: B[n=qrow=l16][k=quad*8+j])
    f16x8 qf[2];
    {
        const float* qrow = q + (((size_t)b * N_ + qt * 64 + w4 * 16 + l16) * H_ + h) * D_;
        #pragma unroll
        for (int kk = 0; kk < 2; ++kk) {
            const float4 a0 = *reinterpret_cast<const float4*>(&qrow[kk * 32 + quad * 8]);
            const float4 a1 = *reinterpret_cast<const float4*>(&qrow[kk * 32 + quad * 8 + 4]);
            qf[kk][0] = (f16)(a0.x * QSCALE); qf[kk][1] = (f16)(a0.y * QSCALE);
            qf[kk][2] = (f16)(a0.z * QSCALE); qf[kk][3] = (f16)(a0.w * QSCALE);
            qf[kk][4] = (f16)(a1.x * QSCALE); qf[kk][5] = (f16)(a1.y * QSCALE);
            qf[kk][6] = (f16)(a1.z * QSCALE); qf[kk][7] = (f16)(a1.w * QSCALE);
        }
    }

    f32x4 o2[4];                        // O^T accum: d = nt*16+quad*4+e, qrow = l16
    #pragma unroll
    for (int nt = 0; nt < 4; ++nt) o2[nt] = (f32x4){0.f, 0.f, 0.f, 0.f};
    float lp = 0.f;

    // ---- precomputed lane-constant LDS byte offsets (within a 32 KB grp region)
    // region layout per buffer: K tile @ buf*16384, V tile @ buf*16384 + 8192.
    const char* grpBase = smem + grp * 32768;
    const int xk  = l16 & 7;
    const int gk0 = quad ^ xk;                       // K granule, kk=0
    // kk=1 granule = gk0 ^ 4  (since (4+quad)^x == (quad^x)^4 for quad<4)
    const int kOff0 = l16 * 128 + gk0 * 16;          // bytes within K tile
    const int kOff1 = l16 * 128 + (gk0 ^ 4) * 16;
    const int gv0 = (2 * quad) ^ xk;                 // V granule, hf=0
    // hf=1 granule = gv0 ^ 1
    const int vOff0 = l16 * 128 + (gv0)     * 16;    // bytes within V tile
    const int vOff1 = l16 * 128 + (gv0 ^ 1) * 16;

    const int rloc = lane >> 3;
    const int csw  = (lane & 7) ^ rloc;

    // prologue: stage tile 0 -> buffer 0
    #pragma unroll
    for (int i = 0; i < 2; ++i) {
        const int r = i * 32 + w4 * 8 + rloc;
        load_lds16(kbase + (size_t)r * 64 + csw * 8,
                   (void*)(grpBase + (i * 32 + w4 * 8) * 128));
        load_lds16(vbase + (size_t)r * M_ + csw * 8,
                   (void*)(grpBase + 8192 + (i * 32 + w4 * 8) * 128));
    }

    #pragma unroll 2
    for (int t = 0; t < NT_; ++t) {
        const int cur = t & 1;                       // static under unroll 2
        __syncthreads();                             // staging of tile t complete

        if (t + 1 < NT_) {
            const f16* kp = kbase + (size_t)(t + 1) * KT * 64;
            const f16* vp = vbase + (size_t)(t + 1) * KT;
            char* dstBase = (char*)grpBase + (cur ^ 1) * 16384;
            #pragma unroll
            for (int i = 0; i < 2; ++i) {
                const int r = i * 32 + w4 * 8 + rloc;
                load_lds16(kp + (size_t)r * 64 + csw * 8,
                           dstBase + (i * 32 + w4 * 8) * 128);
                load_lds16(vp + (size_t)r * M_ + csw * 8,
                           dstBase + 8192 + (i * 32 + w4 * 8) * 128);
            }
        }

        // ---- S^T = K·Q^T : all read addresses = const base + immediate
        const char* kt = grpBase + cur * 16384;
        f32x4 st[4];
        #pragma unroll
        for (int ct = 0; ct < 4; ++ct) st[ct] = (f32x4){0.f, 0.f, 0.f, 0.f};
        #pragma unroll
        for (int ct = 0; ct < 4; ++ct) {
            const f16x8 kf0 = *reinterpret_cast<const f16x8*>(kt + ct * 2048 + kOff0);
            st[ct] = __builtin_amdgcn_mfma_f32_16x16x32_f16(kf0, qf[0], st[ct], 0, 0, 0);
            const f16x8 kf1 = *reinterpret_cast<const f16x8*>(kt + ct * 2048 + kOff1);
            st[ct] = __builtin_amdgcn_mfma_f32_16x16x32_f16(kf1, qf[1], st[ct], 0, 0, 0);
        }

        // ---- P = 2^(S^T) via raw v_exp_f32; pack f16 B-frags; l partials
        f16x4 pf[4];
        #pragma unroll
        for (int ct = 0; ct < 4; ++ct) {
            const float p0 = __builtin_amdgcn_exp2f(st[ct][0]);
            const float p1 = __builtin_amdgcn_exp2f(st[ct][1]);
            const float p2 = __builtin_amdgcn_exp2f(st[ct][2]);
            const float p3 = __builtin_amdgcn_exp2f(st[ct][3]);
            lp += (p0 + p1) + (p2 + p3);
            union { hf16x2 h2[2]; f16x4 v4; } u;
            u.h2[0] = __builtin_amdgcn_cvt_pkrtz(p0, p1);
            u.h2[1] = __builtin_amdgcn_cvt_pkrtz(p2, p3);
            pf[ct] = u.v4;
        }

        // ---- O^T += V^T·P^T : two adjacent f16x4 loads (ds_read2_b64), no unions
        const char* vtile = grpBase + cur * 16384 + 8192;
        #pragma unroll
        for (int hf = 0; hf < 2; ++hf) {
            const int vo = hf ? vOff1 : vOff0;
            #pragma unroll
            for (int nt = 0; nt < 4; ++nt) {
                const f16x4 va = *reinterpret_cast<const f16x4*>(vtile + nt * 2048 + vo);
                const f16x4 vb = *reinterpret_cast<const f16x4*>(vtile + nt * 2048 + vo + 8);
                o2[nt] = __builtin_amdgcn_mfma_f32_16x16x16f16(va, pf[2 * hf],     o2[nt], 0, 0, 0);
                o2[nt] = __builtin_amdgcn_mfma_f32_16x16x16f16(vb, pf[2 * hf + 1], o2[nt], 0, 0, 0);
            }
        }
    }

    // ---- reduce l over quads
    float l = lp;
    l += __shfl_xor(l, 16, 64);
    l += __shfl_xor(l, 32, 64);

    __syncthreads();                    // all staging reads done; safe to overlay
    if (grp == 1) {
        const int base = (w4 * 64 + lane) * 16;
        #pragma unroll
        for (int nt = 0; nt < 4; ++nt)
            *reinterpret_cast<f32x4*>(&sC[base + nt * 4]) = o2[nt];
        if (quad == 0) sL[w4 * 16 + l16] = l;
    }
    __syncthreads();
    if (grp == 0) {
        const int base = (w4 * 64 + lane) * 16;
        const float inv = 1.0f / (l + sL[w4 * 16 + l16]);
        const size_t orow = (((size_t)b * N_ + qt * 64 + w4 * 16 + l16) * H_ + h) * D_;
        #pragma unroll
        for (int nt = 0; nt < 4; ++nt) {
            const f32x4 c = *reinterpret_cast<const f32x4*>(&sC[base + nt * 4]);
            float4 w;
            w.x = (o2[nt][0] + c[0]) * inv;
            w.y = (o2[nt][1] + c[1]) * inv;
            w.z = (o2[nt][2] + c[2]) * inv;
            w.w = (o2[nt][3] + c[3]) * inv;
            *reinterpret_cast<float4*>(&out[orow + nt * 16 + quad * 4]) = w;
        }
    }
}

extern "C" void kernel_launch(void* const* d_in, const int* in_sizes, int n_in,
                              void* d_out, int out_size, void* d_ws, size_t ws_size,
                              hipStream_t stream) {
    const float* q = (const float*)d_in[0];
    const float* k = (const float*)d_in[1];
    const float* v = (const float*)d_in[2];
    float* out = (float*)d_out;

    const size_t ESZ = (size_t)B_ * H_ * N_ * D_;   // 2097152
    f16* kh = (f16*)d_ws;                            // 4 MB
    f16* vh = kh + ESZ;                              // 4 MB

    prep<<<dim3(2560), dim3(256), 0, stream>>>(k, v, kh, vh);
    fa_main<<<dim3(N_ / 64, B_ * H_), dim3(512), 0, stream>>>(q, kh, vh, out);
}